// Round 1
// baseline (134.039 us; speedup 1.0000x reference)
//
#include <hip/hip_runtime.h>
#include <cstdint>
#include <cstring>

// ============================================================================
// NUTS on diagonal Gaussian, exact JAX-semantics replication.
//
// Key facts exploited:
//  * exp(-H) == 0.0f exactly (H ~ 12288) => every leaf has n=1, s=1; the
//    slice variable u and all leaf energies are irrelevant.
//  * v_j is a scalar per doubling => the 31-step leapfrog trajectory is
//    deterministic and independent per (chain, dim). Only 62 per-chain dot
//    products + a tiny per-chain state machine couple dimensions.
//  * theta_m per chain == some leaf's theta (or theta0) => select-by-index.
//
// PRNG: threefry2x32, JAX "partitionable" scheme (default since jax 0.4.36):
//   split(key)[i]      = TF(key, 0, i)            (both outputs = new key)
//   random_bits(key)[i] = y0 ^ y1 of TF(key, 0, i)
// Fallback if bench shows total mismatch: set PARTITIONABLE to 0 (legacy
// iota-pair counter scheme, implemented below as well).
// ============================================================================

#define PARTITIONABLE 1

constexpr int NCHAIN = 128;
constexpr int NDIM   = 16384;
constexpr int VD     = 4;                    // dims per thread (one float4)
constexpr int TPB    = 256;
constexpr int WGPC   = NDIM / (TPB * VD);    // 16 workgroups per chain
constexpr int NW     = NDIM / (64 * VD);     // 64 wave-slices per chain
constexpr int NSLOT  = 62;                   // 2*(26 nodes) + 2*(5 doublings)
constexpr int NNODE  = 26;
constexpr float EPS  = 0.05f;

static_assert(NDIM % (TPB * VD) == 0, "tiling");

// ---------------------------------------------------------------- threefry --
__host__ __device__ static inline void tf2(uint32_t k0, uint32_t k1,
                                           uint32_t x0, uint32_t x1,
                                           uint32_t& o0, uint32_t& o1) {
  const uint32_t ks2 = k0 ^ k1 ^ 0x1BD11BDAu;
  x0 += k0; x1 += k1;
#define TF_R(r) { x0 += x1; x1 = (x1 << (r)) | (x1 >> (32 - (r))); x1 ^= x0; }
  TF_R(13) TF_R(15) TF_R(26) TF_R(6)
  x0 += k1;  x1 += ks2 + 1u;
  TF_R(17) TF_R(29) TF_R(16) TF_R(24)
  x0 += ks2; x1 += k0 + 2u;
  TF_R(13) TF_R(15) TF_R(26) TF_R(6)
  x0 += k0;  x1 += k1 + 3u;
  TF_R(17) TF_R(29) TF_R(16) TF_R(24)
  x0 += k1;  x1 += ks2 + 4u;
  TF_R(13) TF_R(15) TF_R(26) TF_R(6)
  x0 += ks2; x1 += k0 + 5u;
#undef TF_R
  o0 = x0; o1 = x1;
}

// uniform [0,1) from 32 random bits, JAX recipe
__device__ static inline float u01(uint32_t bits) {
  return __uint_as_float((bits >> 9) | 0x3f800000u) - 1.0f;
}

// XLA ErfInv32 (Giles), fma-exact
__device__ static inline float erfinv32(float x) {
  float w = -log1pf(-x * x);
  float p;
  if (w < 5.0f) {
    w -= 2.5f;
    p = 2.81022636e-08f;
    p = fmaf(p, w, 3.43273939e-07f);
    p = fmaf(p, w, -3.5233877e-06f);
    p = fmaf(p, w, -4.39150654e-06f);
    p = fmaf(p, w, 0.00021858087f);
    p = fmaf(p, w, -0.00125372503f);
    p = fmaf(p, w, -0.00417768164f);
    p = fmaf(p, w, 0.246640727f);
    p = fmaf(p, w, 1.50140941f);
  } else {
    w = sqrtf(w) - 3.0f;
    p = -0.000200214257f;
    p = fmaf(p, w, 0.000100950558f);
    p = fmaf(p, w, 0.00134934322f);
    p = fmaf(p, w, -0.00367342844f);
    p = fmaf(p, w, 0.00573950773f);
    p = fmaf(p, w, -0.0076224613f);
    p = fmaf(p, w, 0.00943887047f);
    p = fmaf(p, w, 1.00167406f);
    p = fmaf(p, w, 2.83297682f);
  }
  return p * x;
}

// jax.random.normal: u = uniform(lo=nextafter(-1,0), hi=1); hi-lo == 2.0f exactly
__device__ static inline float norm_from_bits(uint32_t bits) {
  const float lo = __uint_as_float(0xBF7FFFFFu);       // -(1 - 2^-24)
  float u = fmaxf(lo, fmaf(u01(bits), 2.0f, lo));
  return __uint_as_float(0x3FB504F3u) * erfinv32(u);   // sqrt(2) in f32
}

// one uniform[0,1) for chain b from a (B=128,)-shaped jax.random.uniform
__device__ static inline float unif_chain(uint32_t k0, uint32_t k1, int b) {
#if PARTITIONABLE
  uint32_t a, c; tf2(k0, k1, 0u, (uint32_t)b, a, c);
  return u01(a ^ c);
#else
  uint32_t a, c;
  if (b < 64) { tf2(k0, k1, (uint32_t)b, (uint32_t)(b + 64), a, c); return u01(a); }
  else        { tf2(k0, k1, (uint32_t)(b - 64), (uint32_t)b, a, c); return u01(c); }
#endif
}

// ------------------------------------------------------------------ params --
struct TrajParams { int v[5]; };
struct K2Params {
  uint32_t nk0[NNODE], nk1[NNODE];  // buildtree k3 keys, post-order across j
  uint32_t ak0[5], ak1[5];          // main-loop ka keys
  int v[5];
};

// -------------------------------------------------------- K0: r0 + out=th0 --
__global__ void k_init(const float* __restrict__ th0, float* __restrict__ r0,
                       float* __restrict__ out, uint32_t k0, uint32_t k1) {
  int i = blockIdx.x * blockDim.x + threadIdx.x;
#if PARTITIONABLE
  uint32_t a, c; tf2(k0, k1, 0u, (uint32_t)i, a, c);
  r0[i]  = norm_from_bits(a ^ c);
  out[i] = th0[i];
#else
  // legacy: bits[i] = y0(i, i+N/2) for i<N/2 else y1(i-N/2, i)
  const int H = NCHAIN * NDIM / 2;
  uint32_t a, c; tf2(k0, k1, (uint32_t)i, (uint32_t)(i + H), a, c);
  r0[i]      = norm_from_bits(a);
  r0[i + H]  = norm_from_bits(c);
  out[i]     = th0[i];
  out[i + H] = th0[i + H];
#endif
}

// --------------------------------------------- K1/K3: deterministic trajectory
// MODE 0: accumulate u-turn dot partials.  MODE 1: write selected leaf to out.
template <int MODE>
__launch_bounds__(TPB)
__global__ void k_traj(const float* __restrict__ th0g, const float* __restrict__ precg,
                       const float* __restrict__ r0g, float* __restrict__ partials,
                       const int* __restrict__ selg, float* __restrict__ outg,
                       TrajParams P) {
  const int chain   = blockIdx.x / WGPC;
  const int sblk    = blockIdx.x % WGPC;
  const int dimBase = sblk * (TPB * VD) + threadIdx.x * VD;
  const int lane    = threadIdx.x & 63;
  const int wv      = sblk * (TPB / 64) + (threadIdx.x >> 6);   // [0, NW)

  float tha[VD], ra[VD], tho[VD], ro[VD], pc[VD];
  {
    const float4 t = *reinterpret_cast<const float4*>(th0g + (size_t)chain * NDIM + dimBase);
    const float4 r = *reinterpret_cast<const float4*>(r0g  + (size_t)chain * NDIM + dimBase);
    const float4 p = *reinterpret_cast<const float4*>(precg + dimBase);
    tha[0]=t.x; tha[1]=t.y; tha[2]=t.z; tha[3]=t.w;
    ra [0]=r.x; ra [1]=r.y; ra [2]=r.z; ra [3]=r.w;
    pc [0]=p.x; pc [1]=p.y; pc [2]=p.z; pc [3]=p.w;
  }
#pragma unroll
  for (int d = 0; d < VD; ++d) { tho[d] = tha[d]; ro[d] = ra[d]; }

  float near_t[5][VD], near_r[5][VD];   // MODE 0 only (dead in MODE 1)
  float outv[VD];
  int selv = -2;
  if (MODE == 1) selv = selg[chain];     // wave-uniform

  int slot = 0, g = 0;
  bool cur_fwd = true;

#pragma unroll
  for (int j = 0; j < 5; ++j) {
    const bool fwd = P.v[j] > 0;
    if (fwd != cur_fwd) {
#pragma unroll
      for (int d = 0; d < VD; ++d) {
        float t;
        t = tha[d]; tha[d] = tho[d]; tho[d] = t;
        t = ra[d];  ra[d]  = ro[d];  ro[d]  = t;
      }
    }
    cur_fwd = fwd;
    const float e  = fwd ? EPS : -EPS;
    const float he = 0.5f * e;
    const int NL = 1 << j;
#pragma unroll
    for (int i = 0; i < NL; ++i) {
      // leapfrog step on the active endpoint (grad U = prec * theta)
#pragma unroll
      for (int d = 0; d < VD; ++d) {
        float g1 = pc[d] * tha[d];
        ra[d]  = fmaf(-he, g1, ra[d]);
        tha[d] = fmaf(e, ra[d], tha[d]);
        float g2 = pc[d] * tha[d];
        ra[d]  = fmaf(-he, g2, ra[d]);
      }
      if (MODE == 1) {
        if (g == selv) {
#pragma unroll
          for (int d = 0; d < VD; ++d) outv[d] = tha[d];
        }
      }
      g++;
      if (MODE == 0) {
        const int p = __builtin_popcount((unsigned)i);   // push slot
#pragma unroll
        for (int d = 0; d < VD; ++d) { near_t[p][d] = tha[d]; near_r[p][d] = ra[d]; }
        const int m = __builtin_ctz(~(unsigned)i);       // trailing ones of i
#pragma unroll
        for (int k = 0; k < m; ++k) {
          const int s1 = p - 1 - k;                      // first-child near slot
          float d1 = 0.f, d2 = 0.f;
#pragma unroll
          for (int d = 0; d < VD; ++d) {
            float dd = tha[d] - near_t[s1][d];
            d1 = fmaf(dd, near_r[s1][d], d1);            // (th_far-th_near)·r_near
            d2 = fmaf(dd, ra[d], d2);                    // (th_far-th_near)·r_far
          }
#pragma unroll
          for (int off = 32; off > 0; off >>= 1) {
            d1 += __shfl_down(d1, off, 64);
            d2 += __shfl_down(d2, off, 64);
          }
          if (lane == 0) {
            partials[((size_t)(slot    ) * NCHAIN + chain) * NW + wv] = d1;
            partials[((size_t)(slot + 1) * NCHAIN + chain) * NW + wv] = d2;
          }
          slot += 2;
        }
      }
    }
    if (MODE == 0) {
      // main-loop u-turn raw dots: p1=(a-o)·r_a, p2=(a-o)·r_o; K2 maps by v_j
      float p1 = 0.f, p2 = 0.f;
#pragma unroll
      for (int d = 0; d < VD; ++d) {
        float dd = tha[d] - tho[d];
        p1 = fmaf(dd, ra[d], p1);
        p2 = fmaf(dd, ro[d], p2);
      }
#pragma unroll
      for (int off = 32; off > 0; off >>= 1) {
        p1 += __shfl_down(p1, off, 64);
        p2 += __shfl_down(p2, off, 64);
      }
      if (lane == 0) {
        partials[((size_t)(slot    ) * NCHAIN + chain) * NW + wv] = p1;
        partials[((size_t)(slot + 1) * NCHAIN + chain) * NW + wv] = p2;
      }
      slot += 2;
    }
  }
  if (MODE == 1) {
    if (selv >= 0) {
      float4 o; o.x = outv[0]; o.y = outv[1]; o.z = outv[2]; o.w = outv[3];
      *reinterpret_cast<float4*>(outg + (size_t)chain * NDIM + dimBase) = o;
    }
  }
}

// ------------------------------------------------ K_red: fold NW partials ---
__global__ void k_red(const float* __restrict__ partials, float* __restrict__ dots) {
  int w    = (blockIdx.x * blockDim.x + threadIdx.x) >> 6;  // (slot*NCHAIN + b)
  int lane = threadIdx.x & 63;
  if (w >= NSLOT * NCHAIN) return;
  float v = partials[(size_t)w * NW + lane];
#pragma unroll
  for (int off = 32; off > 0; off >>= 1) v += __shfl_down(v, off, 64);
  if (lane == 0) dots[w] = v;
}

// ---------------------------------------- K2: per-chain NUTS state machine --
__global__ void k_logic(const float* __restrict__ dots, int* __restrict__ selg,
                        K2Params P) {
  int b = threadIdx.x;
  if (b >= NCHAIN) return;
  int n = 1, s = 1, sel = -1;
  int slot = 0, nodeidx = 0, g = 0;
  int st_n[6], st_s[6], st_p[6];
  for (int j = 0; j < 5; ++j) {
    float vj = (P.v[j] > 0) ? 1.0f : -1.0f;
    int sp = 0;
    int NL = 1 << j;
    for (int i = 0; i < NL; ++i) {
      st_n[sp] = 1; st_s[sp] = 1; st_p[sp] = g; sp++; g++;   // leaf: n=1,s=1
      int m = __builtin_ctz(~(unsigned)i);
      for (int k = 0; k < m; ++k) {
        int n1 = st_n[sp-2], s1 = st_s[sp-2], p1i = st_p[sp-2];
        int n2 = st_n[sp-1], s2 = st_s[sp-1], p2i = st_p[sp-1];
        float d1 = dots[(size_t)(slot    ) * NCHAIN + b];
        float d2 = dots[(size_t)(slot + 1) * NCHAIN + b];
        slot += 2;
        float uu = unif_chain(P.nk0[nodeidx], P.nk1[nodeidx], b);
        nodeidx++;
        int   dn    = n1 + n2; if (dn < 1) dn = 1;
        bool  flag  = (uu < (float)n2 / (float)dn) && (s1 >= 1);
        int   pm    = flag ? p2i : p1i;
        int   sm    = (s1 != 0 && s2 != 0 &&
                       (vj * d1 >= 0.0f) && (vj * d2 >= 0.0f)) ? 1 : 0;
        int   nm    = n1 + ((s1 >= 1) ? n2 : 0);
        st_n[sp-2] = nm; st_s[sp-2] = sm; st_p[sp-2] = pm;
        sp--;
      }
    }
    int n_p = st_n[0], s_p = st_s[0], th_p = st_p[0];
    float q1 = dots[(size_t)(slot    ) * NCHAIN + b];   // (a-o)·r_a
    float q2 = dots[(size_t)(slot + 1) * NCHAIN + b];   // (a-o)·r_o
    slot += 2;
    float dm1, dm2;                                     // d=(th_f - th_r)
    if (P.v[j] > 0) { dm1 = q2;  dm2 = q1; }            // active endpoint = fwd
    else            { dm1 = -q1; dm2 = -q2; }           // active endpoint = bwd
    float au = unif_chain(P.ak0[j], P.ak1[j], b);
    float ratio = fminf((float)n_p / (float)n, 1.0f);
    bool acc = (au < ratio) && (s >= 1) && (s_p >= 1);
    if (acc) sel = th_p;
    n = n + ((s >= 1) ? n_p : 0);
    s = (s != 0 && s_p != 0 && (dm1 >= 0.0f) && (dm2 >= 0.0f)) ? 1 : 0;
  }
  selg[b] = sel;
}

// ------------------------------------------------------------- host PRNG ---
static inline float host_bits_to_f(uint32_t fb) { float f; std::memcpy(&f, &fb, 4); return f; }

static void host_split(uint32_t k0, uint32_t k1, int nsub, uint32_t* o0, uint32_t* o1) {
#if PARTITIONABLE
  for (int i = 0; i < nsub; ++i) tf2(k0, k1, 0u, (uint32_t)i, o0[i], o1[i]);
#else
  uint32_t A[8], C[8], flat[16];
  for (int i = 0; i < nsub; ++i) tf2(k0, k1, (uint32_t)i, (uint32_t)(nsub + i), A[i], C[i]);
  for (int i = 0; i < nsub; ++i) { flat[i] = A[i]; flat[nsub + i] = C[i]; }
  for (int j = 0; j < nsub; ++j) { o0[j] = flat[2*j]; o1[j] = flat[2*j + 1]; }
#endif
}

static int host_vsign(uint32_t k0, uint32_t k1) {    // sign of normal(kv, ())
  uint32_t a, c; tf2(k0, k1, 0u, 0u, a, c);
#if PARTITIONABLE
  uint32_t bits = a ^ c;
#else
  uint32_t bits = a;                                 // odd-size pad path: y0(0,0)
#endif
  float f  = host_bits_to_f((bits >> 9) | 0x3f800000u) - 1.0f;
  float lo = host_bits_to_f(0xBF7FFFFFu);
  float u  = f * 2.0f + lo;                          // sign(erfinv(u)) = sign(u)
  return (u >= 0.0f) ? 1 : -1;
}

// buildtree k3 keys in post-order (merge-consumption order)
static void gen_nodes(uint32_t k0, uint32_t k1, int j,
                      uint32_t* nk0, uint32_t* nk1, int& idx) {
  if (j == 0) return;
  uint32_t o0[3], o1[3];
  host_split(k0, k1, 3, o0, o1);                     // k1, k2, k3
  gen_nodes(o0[0], o1[0], j - 1, nk0, nk1, idx);
  gen_nodes(o0[1], o1[1], j - 1, nk0, nk1, idx);
  nk0[idx] = o0[2]; nk1[idx] = o1[2]; idx++;
}

// ---------------------------------------------------------------- launch ----
extern "C" void kernel_launch(void* const* d_in, const int* in_sizes, int n_in,
                              void* d_out, int out_size, void* d_ws, size_t ws_size,
                              hipStream_t stream) {
  const float* th0  = (const float*)d_in[0];
  const float* prec = (const float*)d_in[1];
  float* out = (float*)d_out;

  float* r0       = (float*)d_ws;                               // 8 MB
  float* partials = r0 + (size_t)NCHAIN * NDIM;                 // ~2 MB
  float* dots     = partials + (size_t)NSLOT * NCHAIN * NW;     // ~32 KB
  int*   sel      = (int*)(dots + (size_t)NSLOT * NCHAIN);      // 512 B
  // total ws use ~10.5 MB

  // ---- replicate jax key schedule on host (deterministic, same every call)
  uint32_t key0 = 0u, key1 = 42u;                               // jax.random.key(42)
  uint32_t s0[4], s1[4];
  host_split(key0, key1, 3, s0, s1);                            // kr, ku, key
  const uint32_t kr0 = s0[0], kr1 = s1[0];                      // r0 normals
  key0 = s0[2]; key1 = s1[2];                                   // (ku unused: u==0)

  K2Params P2; TrajParams PT;
  int idx = 0;
  for (int j = 0; j < 5; ++j) {
    host_split(key0, key1, 4, s0, s1);                          // key, kv, kt, ka
    key0 = s0[0]; key1 = s1[0];
    int v = host_vsign(s0[1], s1[1]);
    P2.v[j] = v; PT.v[j] = v;
    gen_nodes(s0[2], s1[2], j, P2.nk0, P2.nk1, idx);            // kt recursion
    P2.ak0[j] = s0[3]; P2.ak1[j] = s1[3];                       // ka
  }

  // ---- K0: r0 = normal(kr), out = theta0
#if PARTITIONABLE
  k_init<<<dim3((NCHAIN * NDIM) / TPB), dim3(TPB), 0, stream>>>(th0, r0, out, kr0, kr1);
#else
  k_init<<<dim3((NCHAIN * NDIM / 2) / TPB), dim3(TPB), 0, stream>>>(th0, r0, out, kr0, kr1);
#endif
  // ---- K1: trajectory + dot partials
  k_traj<0><<<dim3(NCHAIN * WGPC), dim3(TPB), 0, stream>>>(
      th0, prec, r0, partials, sel, out, PT);
  // ---- fold partials (62*128 waves, 64 values each)
  k_red<<<dim3((NSLOT * NCHAIN * 64) / TPB), dim3(TPB), 0, stream>>>(partials, dots);
  // ---- per-chain state machine -> selected leaf index
  k_logic<<<dim3(1), dim3(NCHAIN), 0, stream>>>(dots, sel, P2);
  // ---- re-simulate, write selected leaf theta
  k_traj<1><<<dim3(NCHAIN * WGPC), dim3(TPB), 0, stream>>>(
      th0, prec, r0, partials, sel, out, PT);
}

// Round 2
// 125.744 us; speedup vs baseline: 1.0660x; 1.0660x over previous
//
#include <hip/hip_runtime.h>
#include <cstdint>
#include <cstring>

// ============================================================================
// NUTS on diagonal Gaussian, exact JAX-semantics replication.
//
// R1 -> R2 changes (theory: k_traj was scratch-spill + DS-shuffle bound):
//  * DPP-based wave reduction (VALU pipe) replaces __shfl_down (DS pipe).
//  * __launch_bounds__(256,4): allow ~128 VGPRs so the 40-float near-stack
//    stays in registers (R1 compiled to VGPR=32 => everything spilled).
//  * r0 regenerated inline via threefry in both trajectory kernels; k_init
//    and the 8MB r0 buffer are gone. MODE 1 writes every chain's output
//    (theta0 when sel==-1), so d_out needs no separate init.
// ============================================================================

#define PARTITIONABLE 1

constexpr int NCHAIN = 128;
constexpr int NDIM   = 16384;
constexpr int VD     = 4;                    // dims per thread (one float4)
constexpr int TPB    = 256;
constexpr int WGPC   = NDIM / (TPB * VD);    // 16 workgroups per chain
constexpr int NW     = NDIM / (64 * VD);     // 64 wave-slices per chain
constexpr int NSLOT  = 62;                   // 2*(26 nodes) + 2*(5 doublings)
constexpr int NNODE  = 26;
constexpr float EPS  = 0.05f;

static_assert(NDIM % (TPB * VD) == 0, "tiling");

// ---------------------------------------------------------------- threefry --
__host__ __device__ static inline void tf2(uint32_t k0, uint32_t k1,
                                           uint32_t x0, uint32_t x1,
                                           uint32_t& o0, uint32_t& o1) {
  const uint32_t ks2 = k0 ^ k1 ^ 0x1BD11BDAu;
  x0 += k0; x1 += k1;
#define TF_R(r) { x0 += x1; x1 = (x1 << (r)) | (x1 >> (32 - (r))); x1 ^= x0; }
  TF_R(13) TF_R(15) TF_R(26) TF_R(6)
  x0 += k1;  x1 += ks2 + 1u;
  TF_R(17) TF_R(29) TF_R(16) TF_R(24)
  x0 += ks2; x1 += k0 + 2u;
  TF_R(13) TF_R(15) TF_R(26) TF_R(6)
  x0 += k0;  x1 += k1 + 3u;
  TF_R(17) TF_R(29) TF_R(16) TF_R(24)
  x0 += k1;  x1 += ks2 + 4u;
  TF_R(13) TF_R(15) TF_R(26) TF_R(6)
  x0 += ks2; x1 += k0 + 5u;
#undef TF_R
  o0 = x0; o1 = x1;
}

// uniform [0,1) from 32 random bits, JAX recipe
__device__ static inline float u01(uint32_t bits) {
  return __uint_as_float((bits >> 9) | 0x3f800000u) - 1.0f;
}

// XLA ErfInv32 (Giles), fma-exact
__device__ static inline float erfinv32(float x) {
  float w = -log1pf(-x * x);
  float p;
  if (w < 5.0f) {
    w -= 2.5f;
    p = 2.81022636e-08f;
    p = fmaf(p, w, 3.43273939e-07f);
    p = fmaf(p, w, -3.5233877e-06f);
    p = fmaf(p, w, -4.39150654e-06f);
    p = fmaf(p, w, 0.00021858087f);
    p = fmaf(p, w, -0.00125372503f);
    p = fmaf(p, w, -0.00417768164f);
    p = fmaf(p, w, 0.246640727f);
    p = fmaf(p, w, 1.50140941f);
  } else {
    w = sqrtf(w) - 3.0f;
    p = -0.000200214257f;
    p = fmaf(p, w, 0.000100950558f);
    p = fmaf(p, w, 0.00134934322f);
    p = fmaf(p, w, -0.00367342844f);
    p = fmaf(p, w, 0.00573950773f);
    p = fmaf(p, w, -0.0076224613f);
    p = fmaf(p, w, 0.00943887047f);
    p = fmaf(p, w, 1.00167406f);
    p = fmaf(p, w, 2.83297682f);
  }
  return p * x;
}

// jax.random.normal: u = uniform(lo=nextafter(-1,0), hi=1); hi-lo == 2.0f exactly
__device__ static inline float norm_from_bits(uint32_t bits) {
  const float lo = __uint_as_float(0xBF7FFFFFu);       // -(1 - 2^-24)
  float u = fmaxf(lo, fmaf(u01(bits), 2.0f, lo));
  return __uint_as_float(0x3FB504F3u) * erfinv32(u);   // sqrt(2) in f32
}

// r0 normal for flat element index i of jax.random.normal(kr, (B,D))
__device__ static inline float r0_elem(uint32_t k0, uint32_t k1, uint32_t i) {
#if PARTITIONABLE
  uint32_t a, c; tf2(k0, k1, 0u, i, a, c);
  return norm_from_bits(a ^ c);
#else
  const uint32_t H = (uint32_t)(NCHAIN * NDIM / 2);
  uint32_t a, c;
  if (i < H) { tf2(k0, k1, i, i + H, a, c); return norm_from_bits(a); }
  else       { tf2(k0, k1, i - H, i, a, c); return norm_from_bits(c); }
#endif
}

// one uniform[0,1) for chain b from a (B=128,)-shaped jax.random.uniform
__device__ static inline float unif_chain(uint32_t k0, uint32_t k1, int b) {
#if PARTITIONABLE
  uint32_t a, c; tf2(k0, k1, 0u, (uint32_t)b, a, c);
  return u01(a ^ c);
#else
  uint32_t a, c;
  if (b < 64) { tf2(k0, k1, (uint32_t)b, (uint32_t)(b + 64), a, c); return u01(a); }
  else        { tf2(k0, k1, (uint32_t)(b - 64), (uint32_t)b, a, c); return u01(c); }
#endif
}

// ------------------------------------------------- DPP 64-lane sum (lane 63)
// LLVM AMDGPUAtomicOptimizer gfx9 sequence: row_shr 1/2/4/8, row_bcast 15/31.
#define DPP_ADD(x, ctrl, rm)                                                   \
  (x) += __int_as_float(__builtin_amdgcn_update_dpp(                           \
      0, __float_as_int(x), (ctrl), (rm), 0xf, true));

__device__ static inline float wave_sum63(float x) {
  DPP_ADD(x, 0x111, 0xf)   // row_shr:1
  DPP_ADD(x, 0x112, 0xf)   // row_shr:2
  DPP_ADD(x, 0x114, 0xf)   // row_shr:4
  DPP_ADD(x, 0x118, 0xf)   // row_shr:8
  DPP_ADD(x, 0x142, 0xa)   // row_bcast:15 -> rows 1,3
  DPP_ADD(x, 0x143, 0xc)   // row_bcast:31 -> rows 2,3
  return x;                // lane 63 holds the 64-lane sum
}

// ------------------------------------------------------------------ params --
struct TrajParams { int v[5]; };
struct K2Params {
  uint32_t nk0[NNODE], nk1[NNODE];  // buildtree k3 keys, post-order across j
  uint32_t ak0[5], ak1[5];          // main-loop ka keys
  int v[5];
};

// --------------------------------------------- K1/K3: deterministic trajectory
// MODE 0: accumulate u-turn dot partials.  MODE 1: write selected leaf to out
//         (theta0 when sel==-1) — covers every element of d_out.
template <int MODE>
__launch_bounds__(TPB, 4)
__global__ void k_traj(const float* __restrict__ th0g, const float* __restrict__ precg,
                       uint32_t kr0, uint32_t kr1,
                       float* __restrict__ partials,
                       const int* __restrict__ selg, float* __restrict__ outg,
                       TrajParams P) {
  const int chain   = blockIdx.x / WGPC;
  const int sblk    = blockIdx.x % WGPC;
  const int dimBase = sblk * (TPB * VD) + threadIdx.x * VD;
  const int lane    = threadIdx.x & 63;
  const int wv      = sblk * (TPB / 64) + (threadIdx.x >> 6);   // [0, NW)
  const uint32_t flat = (uint32_t)chain * NDIM + dimBase;

  float tha[VD], ra[VD], tho[VD], ro[VD], pc[VD];
  {
    const float4 t = *reinterpret_cast<const float4*>(th0g + (size_t)chain * NDIM + dimBase);
    const float4 p = *reinterpret_cast<const float4*>(precg + dimBase);
    tha[0]=t.x; tha[1]=t.y; tha[2]=t.z; tha[3]=t.w;
    pc [0]=p.x; pc [1]=p.y; pc [2]=p.z; pc [3]=p.w;
  }
#pragma unroll
  for (int d = 0; d < VD; ++d) ra[d] = r0_elem(kr0, kr1, flat + (uint32_t)d);
#pragma unroll
  for (int d = 0; d < VD; ++d) { tho[d] = tha[d]; ro[d] = ra[d]; }

  float near_t[5][VD], near_r[5][VD];   // MODE 0 only (dead in MODE 1)
  float outv[VD];
  int selv = -2;
  if (MODE == 1) {
    selv = selg[chain];                  // wave-uniform
#pragma unroll
    for (int d = 0; d < VD; ++d) outv[d] = tha[d];   // default: theta0
  }

  int slot = 0, g = 0;
  bool cur_fwd = true;

#pragma unroll
  for (int j = 0; j < 5; ++j) {
    const bool fwd = P.v[j] > 0;
    if (fwd != cur_fwd) {
#pragma unroll
      for (int d = 0; d < VD; ++d) {
        float t;
        t = tha[d]; tha[d] = tho[d]; tho[d] = t;
        t = ra[d];  ra[d]  = ro[d];  ro[d]  = t;
      }
    }
    cur_fwd = fwd;
    const float e  = fwd ? EPS : -EPS;
    const float he = 0.5f * e;
    const int NL = 1 << j;
#pragma unroll
    for (int i = 0; i < NL; ++i) {
      // leapfrog step on the active endpoint (grad U = prec * theta)
#pragma unroll
      for (int d = 0; d < VD; ++d) {
        float g1 = pc[d] * tha[d];
        ra[d]  = fmaf(-he, g1, ra[d]);
        tha[d] = fmaf(e, ra[d], tha[d]);
        float g2 = pc[d] * tha[d];
        ra[d]  = fmaf(-he, g2, ra[d]);
      }
      if (MODE == 1) {
        if (g == selv) {
#pragma unroll
          for (int d = 0; d < VD; ++d) outv[d] = tha[d];
        }
      }
      g++;
      if (MODE == 0) {
        const int p = __builtin_popcount((unsigned)i);   // push slot
#pragma unroll
        for (int d = 0; d < VD; ++d) { near_t[p][d] = tha[d]; near_r[p][d] = ra[d]; }
        const int m = __builtin_ctz(~(unsigned)i);       // trailing ones of i
#pragma unroll
        for (int k = 0; k < m; ++k) {
          const int s1 = p - 1 - k;                      // first-child near slot
          float d1 = 0.f, d2 = 0.f;
#pragma unroll
          for (int d = 0; d < VD; ++d) {
            float dd = tha[d] - near_t[s1][d];
            d1 = fmaf(dd, near_r[s1][d], d1);            // (th_far-th_near)·r_near
            d2 = fmaf(dd, ra[d], d2);                    // (th_far-th_near)·r_far
          }
          d1 = wave_sum63(d1);
          d2 = wave_sum63(d2);
          if (lane == 63) {
            partials[((size_t)(slot    ) * NCHAIN + chain) * NW + wv] = d1;
            partials[((size_t)(slot + 1) * NCHAIN + chain) * NW + wv] = d2;
          }
          slot += 2;
        }
      }
    }
    if (MODE == 0) {
      // main-loop u-turn raw dots: p1=(a-o)·r_a, p2=(a-o)·r_o; K2 maps by v_j
      float p1 = 0.f, p2 = 0.f;
#pragma unroll
      for (int d = 0; d < VD; ++d) {
        float dd = tha[d] - tho[d];
        p1 = fmaf(dd, ra[d], p1);
        p2 = fmaf(dd, ro[d], p2);
      }
      p1 = wave_sum63(p1);
      p2 = wave_sum63(p2);
      if (lane == 63) {
        partials[((size_t)(slot    ) * NCHAIN + chain) * NW + wv] = p1;
        partials[((size_t)(slot + 1) * NCHAIN + chain) * NW + wv] = p2;
      }
      slot += 2;
    }
  }
  if (MODE == 1) {
    float4 o; o.x = outv[0]; o.y = outv[1]; o.z = outv[2]; o.w = outv[3];
    *reinterpret_cast<float4*>(outg + (size_t)chain * NDIM + dimBase) = o;
  }
}

// ------------------------------------------------ K_red: fold NW partials ---
__global__ void k_red(const float* __restrict__ partials, float* __restrict__ dots) {
  int w    = (blockIdx.x * blockDim.x + threadIdx.x) >> 6;  // (slot*NCHAIN + b)
  int lane = threadIdx.x & 63;
  if (w >= NSLOT * NCHAIN) return;
  float v = partials[(size_t)w * NW + lane];
  v = wave_sum63(v);
  if (lane == 63) dots[w] = v;
}

// ---------------------------------------- K2: per-chain NUTS state machine --
__global__ void k_logic(const float* __restrict__ dots, int* __restrict__ selg,
                        K2Params P) {
  int b = threadIdx.x;
  if (b >= NCHAIN) return;
  int n = 1, s = 1, sel = -1;
  int slot = 0, nodeidx = 0, g = 0;
  int st_n[6], st_s[6], st_p[6];
  for (int j = 0; j < 5; ++j) {
    float vj = (P.v[j] > 0) ? 1.0f : -1.0f;
    int sp = 0;
    int NL = 1 << j;
    for (int i = 0; i < NL; ++i) {
      st_n[sp] = 1; st_s[sp] = 1; st_p[sp] = g; sp++; g++;   // leaf: n=1,s=1
      int m = __builtin_ctz(~(unsigned)i);
      for (int k = 0; k < m; ++k) {
        int n1 = st_n[sp-2], s1 = st_s[sp-2], p1i = st_p[sp-2];
        int n2 = st_n[sp-1], s2 = st_s[sp-1], p2i = st_p[sp-1];
        float d1 = dots[(size_t)(slot    ) * NCHAIN + b];
        float d2 = dots[(size_t)(slot + 1) * NCHAIN + b];
        slot += 2;
        float uu = unif_chain(P.nk0[nodeidx], P.nk1[nodeidx], b);
        nodeidx++;
        int   dn    = n1 + n2; if (dn < 1) dn = 1;
        bool  flag  = (uu < (float)n2 / (float)dn) && (s1 >= 1);
        int   pm    = flag ? p2i : p1i;
        int   sm    = (s1 != 0 && s2 != 0 &&
                       (vj * d1 >= 0.0f) && (vj * d2 >= 0.0f)) ? 1 : 0;
        int   nm    = n1 + ((s1 >= 1) ? n2 : 0);
        st_n[sp-2] = nm; st_s[sp-2] = sm; st_p[sp-2] = pm;
        sp--;
      }
    }
    int n_p = st_n[0], s_p = st_s[0], th_p = st_p[0];
    float q1 = dots[(size_t)(slot    ) * NCHAIN + b];   // (a-o)·r_a
    float q2 = dots[(size_t)(slot + 1) * NCHAIN + b];   // (a-o)·r_o
    slot += 2;
    float dm1, dm2;                                     // d=(th_f - th_r)
    if (P.v[j] > 0) { dm1 = q2;  dm2 = q1; }            // active endpoint = fwd
    else            { dm1 = -q1; dm2 = -q2; }           // active endpoint = bwd
    float au = unif_chain(P.ak0[j], P.ak1[j], b);
    float ratio = fminf((float)n_p / (float)n, 1.0f);
    bool acc = (au < ratio) && (s >= 1) && (s_p >= 1);
    if (acc) sel = th_p;
    n = n + ((s >= 1) ? n_p : 0);
    s = (s != 0 && s_p != 0 && (dm1 >= 0.0f) && (dm2 >= 0.0f)) ? 1 : 0;
  }
  selg[b] = sel;
}

// ------------------------------------------------------------- host PRNG ---
static inline float host_bits_to_f(uint32_t fb) { float f; std::memcpy(&f, &fb, 4); return f; }

static void host_split(uint32_t k0, uint32_t k1, int nsub, uint32_t* o0, uint32_t* o1) {
#if PARTITIONABLE
  for (int i = 0; i < nsub; ++i) tf2(k0, k1, 0u, (uint32_t)i, o0[i], o1[i]);
#else
  uint32_t A[8], C[8], flat[16];
  for (int i = 0; i < nsub; ++i) tf2(k0, k1, (uint32_t)i, (uint32_t)(nsub + i), A[i], C[i]);
  for (int i = 0; i < nsub; ++i) { flat[i] = A[i]; flat[nsub + i] = C[i]; }
  for (int j = 0; j < nsub; ++j) { o0[j] = flat[2*j]; o1[j] = flat[2*j + 1]; }
#endif
}

static int host_vsign(uint32_t k0, uint32_t k1) {    // sign of normal(kv, ())
  uint32_t a, c; tf2(k0, k1, 0u, 0u, a, c);
#if PARTITIONABLE
  uint32_t bits = a ^ c;
#else
  uint32_t bits = a;                                 // odd-size pad path: y0(0,0)
#endif
  float f  = host_bits_to_f((bits >> 9) | 0x3f800000u) - 1.0f;
  float lo = host_bits_to_f(0xBF7FFFFFu);
  float u  = f * 2.0f + lo;                          // sign(erfinv(u)) = sign(u)
  return (u >= 0.0f) ? 1 : -1;
}

// buildtree k3 keys in post-order (merge-consumption order)
static void gen_nodes(uint32_t k0, uint32_t k1, int j,
                      uint32_t* nk0, uint32_t* nk1, int& idx) {
  if (j == 0) return;
  uint32_t o0[3], o1[3];
  host_split(k0, k1, 3, o0, o1);                     // k1, k2, k3
  gen_nodes(o0[0], o1[0], j - 1, nk0, nk1, idx);
  gen_nodes(o0[1], o1[1], j - 1, nk0, nk1, idx);
  nk0[idx] = o0[2]; nk1[idx] = o1[2]; idx++;
}

// ---------------------------------------------------------------- launch ----
extern "C" void kernel_launch(void* const* d_in, const int* in_sizes, int n_in,
                              void* d_out, int out_size, void* d_ws, size_t ws_size,
                              hipStream_t stream) {
  const float* th0  = (const float*)d_in[0];
  const float* prec = (const float*)d_in[1];
  float* out = (float*)d_out;

  float* partials = (float*)d_ws;                               // ~2 MB
  float* dots     = partials + (size_t)NSLOT * NCHAIN * NW;     // ~32 KB
  int*   sel      = (int*)(dots + (size_t)NSLOT * NCHAIN);      // 512 B

  // ---- replicate jax key schedule on host (deterministic, same every call)
  uint32_t key0 = 0u, key1 = 42u;                               // jax.random.key(42)
  uint32_t s0[4], s1[4];
  host_split(key0, key1, 3, s0, s1);                            // kr, ku, key
  const uint32_t kr0 = s0[0], kr1 = s1[0];                      // r0 normals
  key0 = s0[2]; key1 = s1[2];                                   // (ku unused: u==0)

  K2Params P2; TrajParams PT;
  int idx = 0;
  for (int j = 0; j < 5; ++j) {
    host_split(key0, key1, 4, s0, s1);                          // key, kv, kt, ka
    key0 = s0[0]; key1 = s1[0];
    int v = host_vsign(s0[1], s1[1]);
    P2.v[j] = v; PT.v[j] = v;
    gen_nodes(s0[2], s1[2], j, P2.nk0, P2.nk1, idx);            // kt recursion
    P2.ak0[j] = s0[3]; P2.ak1[j] = s1[3];                       // ka
  }

  // ---- K1: trajectory + dot partials (r0 generated inline)
  k_traj<0><<<dim3(NCHAIN * WGPC), dim3(TPB), 0, stream>>>(
      th0, prec, kr0, kr1, partials, sel, out, PT);
  // ---- fold partials (62*128 waves, 64 values each)
  k_red<<<dim3((NSLOT * NCHAIN * 64) / TPB), dim3(TPB), 0, stream>>>(partials, dots);
  // ---- per-chain state machine -> selected leaf index
  k_logic<<<dim3(1), dim3(NCHAIN), 0, stream>>>(dots, sel, P2);
  // ---- re-simulate, write selected leaf theta (all chains)
  k_traj<1><<<dim3(NCHAIN * WGPC), dim3(TPB), 0, stream>>>(
      th0, prec, kr0, kr1, partials, sel, out, PT);
}